// Round 1
// baseline (632.748 us; speedup 1.0000x reference)
//
#include <hip/hip_runtime.h>
#include <hip/hip_bf16.h>
#include <math.h>

#define DIMX 1024
#define SEQ  1024
#define HD   64
#define QH   2
#define TH   14
#define STEPS 2048
#define QKVN 2688   // 3*896
#define LN_EPS 1e-5f

typedef __bf16 bf16x8 __attribute__((ext_vector_type(8)));
typedef float  f32x4  __attribute__((ext_vector_type(4)));

__device__ inline unsigned short f2b_rne(float f) {
  unsigned int u = __float_as_uint(f);
  unsigned int r = (u + 0x7FFF + ((u >> 16) & 1)) >> 16;
  return (unsigned short)r;
}

__device__ inline float waveRedSum(float v) {
  #pragma unroll
  for (int off = 32; off; off >>= 1) v += __shfl_xor(v, off, 64);
  return v;
}
__device__ inline float waveRedMax(float v) {
  #pragma unroll
  for (int off = 32; off; off >>= 1) v = fmaxf(v, __shfl_xor(v, off, 64));
  return v;
}

// ---------------- cos table ----------------
__global__ void k_table(float* __restrict__ tbl) {
  int t = blockIdx.x * blockDim.x + threadIdx.x;
  if (t < STEPS) tbl[t] = cosf((float)t * (float)(2.0 * M_PI / (STEPS - 1)));
}

// ---------------- f32 -> bf16 convert ----------------
__global__ void k_f2b(const float* __restrict__ src, unsigned short* __restrict__ dst, int n) {
  int i = (blockIdx.x * blockDim.x + threadIdx.x) * 4;
  if (i >= n) return;
  float4 v = *reinterpret_cast<const float4*>(src + i);
  ushort4 o;
  o.x = f2b_rne(v.x); o.y = f2b_rne(v.y); o.z = f2b_rne(v.z); o.w = f2b_rne(v.w);
  *reinterpret_cast<ushort4*>(dst + i) = o;
}

// ---------------- quantum prep: qs = tanh(LN(xh@qsW^T+b)); amp, u=phase*freq*c ----------------
__global__ __launch_bounds__(128) void k_qprep(
    const float* __restrict__ x, const float* __restrict__ qsW,
    const float* __restrict__ qsb, const float* __restrict__ lng,
    const float* __restrict__ lnb, const float* __restrict__ qfreq,
    float* __restrict__ amp, float* __restrict__ u) {
  int b = blockIdx.x; int h = b >> 10; int i = b & 1023;
  int o = threadIdx.x;  // 0..127
  __shared__ float xrow[HD];
  __shared__ float red[4];
  if (o < HD) xrow[o] = x[i * DIMX + h * HD + o];
  __syncthreads();
  float s = qsb[o];
  #pragma unroll
  for (int d = 0; d < HD; d += 4) {
    float4 w = *reinterpret_cast<const float4*>(qsW + o * HD + d);
    float4 xv = *reinterpret_cast<const float4*>(&xrow[d]);
    s += xv.x * w.x + xv.y * w.y + xv.z * w.z + xv.w * w.w;
  }
  int wid = o >> 6, lane = o & 63;
  float ws = waveRedSum(s);
  if (lane == 0) red[wid] = ws;
  __syncthreads();
  float mu = (red[0] + red[1]) * (1.0f / 128.0f);
  float dv = s - mu;
  float ws2 = waveRedSum(dv * dv);
  if (lane == 0) red[2 + wid] = ws2;
  __syncthreads();
  float var = (red[2] + red[3]) * (1.0f / 128.0f);
  float y = dv * rsqrtf(var + LN_EPS) * lng[o] + lnb[o];
  float q = tanhf(y);
  const float c = 325.9493234522016f;  // 2048/(2*pi)
  if (o < HD) amp[(h * 1024 + i) * HD + o] = q;
  else        u[(h * 1024 + i) * HD + (o - HD)] = q * (qfreq[h] * c);
}

// ---------------- quantum attention: 4 rows per block ----------------
__global__ __launch_bounds__(256) void k_qattn(
    const float* __restrict__ x, const float* __restrict__ tbl,
    const float* __restrict__ amp, const float* __restrict__ u,
    const float* __restrict__ qshift, unsigned short* __restrict__ concat) {
  int blk = blockIdx.x; int h = blk >> 8; int ib = blk & 255;
  int i0 = ib * 4;
  int t = threadIdx.x;
  __shared__ float  stbl[STEPS];      // 8KB
  __shared__ float2 uamp[4][HD];      // 2KB (u'+s0, amp)
  __shared__ float  p[4][SEQ];        // 16KB
  __shared__ float  rowsum[4];
  __shared__ float  part[4][4][HD];   // 4KB
  for (int k = t; k < STEPS; k += 256) stbl[k] = tbl[k];
  const float c = 325.9493234522016f;
  float s0 = qshift[h] * c;
  for (int k = t; k < 4 * HD; k += 256) {
    int ii = k >> 6, d = k & 63;
    uamp[ii][d] = make_float2(u[(h * 1024 + i0 + ii) * HD + d] + s0,
                              amp[(h * 1024 + i0 + ii) * HD + d]);
  }
  __syncthreads();
  const float inv2048 = 1.0f / 2048.0f;
  for (int jt = 0; jt < 4; ++jt) {
    int j = jt * 256 + t;
    const float* uj = &u[(h * 1024 + j) * HD];
    const float* aj = &amp[(h * 1024 + j) * HD];
    float acc[4] = {0.f, 0.f, 0.f, 0.f};
    for (int d0 = 0; d0 < HD; d0 += 4) {
      float4 u4 = *reinterpret_cast<const float4*>(uj + d0);
      float4 a4 = *reinterpret_cast<const float4*>(aj + d0);
      #pragma unroll
      for (int e = 0; e < 4; ++e) {
        float uje = (e == 0) ? u4.x : (e == 1) ? u4.y : (e == 2) ? u4.z : u4.w;
        float aje = (e == 0) ? a4.x : (e == 1) ? a4.y : (e == 2) ? a4.z : a4.w;
        int d = d0 + e;
        #pragma unroll
        for (int ii = 0; ii < 4; ++ii) {
          float2 ua = uamp[ii][d];
          float val = ua.x - uje;
          float q = floorf(val * inv2048);
          float m = fmaf(-2048.0f, q, val);
          int idx = ((int)m) & 2047;
          acc[ii] += ua.y * aje * stbl[idx];
        }
      }
    }
    p[0][j] = acc[0]; p[1][j] = acc[1]; p[2][j] = acc[2]; p[3][j] = acc[3];
  }
  __syncthreads();
  // softmax: wave w handles row w (scale 1/8 folded into exp)
  {
    int wid = t >> 6, lane = t & 63;
    float mx = -1e30f;
    for (int jj = 0; jj < 16; ++jj) mx = fmaxf(mx, p[wid][jj * 64 + lane]);
    mx = waveRedMax(mx);
    float sum = 0.f;
    for (int jj = 0; jj < 16; ++jj) {
      int j = jj * 64 + lane;
      float e = __expf((p[wid][j] - mx) * 0.125f);
      p[wid][j] = e;
      sum += e;
    }
    sum = waveRedSum(sum);
    if (lane == 0) rowsum[wid] = 1.0f / sum;
  }
  __syncthreads();
  // PV: out[i][d] = sum_j p[i][j] * x[j][h*64+d]
  {
    int d = t & 63, cch = t >> 6;
    float acc[4] = {0.f, 0.f, 0.f, 0.f};
    const float* xp = x + h * HD + d;
    for (int j = cch * 256; j < cch * 256 + 256; ++j) {
      float xv = xp[j * DIMX];
      #pragma unroll
      for (int ii = 0; ii < 4; ++ii) acc[ii] += p[ii][j] * xv;
    }
    #pragma unroll
    for (int ii = 0; ii < 4; ++ii) part[cch][ii][d] = acc[ii];
  }
  __syncthreads();
  {
    int ii = t >> 6, dd = t & 63;
    float o = (part[0][ii][dd] + part[1][ii][dd] + part[2][ii][dd] + part[3][ii][dd]) * rowsum[ii];
    concat[(i0 + ii) * DIMX + h * HD + dd] = f2b_rne(o);
  }
}

// ---------------- traditional attention: 16 rows per block ----------------
__global__ __launch_bounds__(256) void k_tattn(
    const float* __restrict__ qkv, unsigned short* __restrict__ concat) {
  int h = blockIdx.y, ib = blockIdx.x, i0 = ib * 16;
  int t = threadIdx.x;
  __shared__ float q16[16][HD];   // 4KB (pre-scaled by 1/8)
  __shared__ float p[SEQ][16];    // 64KB
  __shared__ float rsum[16];
  for (int k = t; k < 16 * HD; k += 256) {
    int r = k >> 6, d = k & 63;
    q16[r][d] = qkv[(size_t)(i0 + r) * QKVN + h * HD + d] * 0.125f;
  }
  __syncthreads();
  // scores
  for (int jt = 0; jt < 4; ++jt) {
    int j = jt * 256 + t;
    const float* kp = qkv + (size_t)j * QKVN + 896 + h * HD;
    float4 kreg[16];
    #pragma unroll
    for (int q = 0; q < 16; ++q) kreg[q] = *reinterpret_cast<const float4*>(kp + q * 4);
    float accr[16];
    #pragma unroll
    for (int r = 0; r < 16; ++r) {
      float a = 0.f;
      #pragma unroll
      for (int q = 0; q < 16; ++q) {
        float4 qv = *reinterpret_cast<const float4*>(&q16[r][q * 4]);
        a += qv.x * kreg[q].x + qv.y * kreg[q].y + qv.z * kreg[q].z + qv.w * kreg[q].w;
      }
      accr[r] = a;
    }
    #pragma unroll
    for (int q = 0; q < 4; ++q) {
      float4 o = make_float4(accr[q * 4], accr[q * 4 + 1], accr[q * 4 + 2], accr[q * 4 + 3]);
      *reinterpret_cast<float4*>(&p[j][q * 4]) = o;
    }
  }
  __syncthreads();
  // softmax: wave w handles rows 4w..4w+3 (p cols 4w..4w+3)
  {
    int wid = t >> 6, lane = t & 63;
    float4 mx = make_float4(-1e30f, -1e30f, -1e30f, -1e30f);
    for (int jj = 0; jj < 16; ++jj) {
      float4 v = *reinterpret_cast<const float4*>(&p[jj * 64 + lane][wid * 4]);
      mx.x = fmaxf(mx.x, v.x); mx.y = fmaxf(mx.y, v.y);
      mx.z = fmaxf(mx.z, v.z); mx.w = fmaxf(mx.w, v.w);
    }
    mx.x = waveRedMax(mx.x); mx.y = waveRedMax(mx.y);
    mx.z = waveRedMax(mx.z); mx.w = waveRedMax(mx.w);
    float4 sm = make_float4(0.f, 0.f, 0.f, 0.f);
    for (int jj = 0; jj < 16; ++jj) {
      int j = jj * 64 + lane;
      float4 v = *reinterpret_cast<const float4*>(&p[j][wid * 4]);
      v.x = __expf(v.x - mx.x); v.y = __expf(v.y - mx.y);
      v.z = __expf(v.z - mx.z); v.w = __expf(v.w - mx.w);
      *reinterpret_cast<float4*>(&p[j][wid * 4]) = v;
      sm.x += v.x; sm.y += v.y; sm.z += v.z; sm.w += v.w;
    }
    sm.x = waveRedSum(sm.x); sm.y = waveRedSum(sm.y);
    sm.z = waveRedSum(sm.z); sm.w = waveRedSum(sm.w);
    if (lane == 0) {
      rsum[wid * 4 + 0] = 1.0f / sm.x; rsum[wid * 4 + 1] = 1.0f / sm.y;
      rsum[wid * 4 + 2] = 1.0f / sm.z; rsum[wid * 4 + 3] = 1.0f / sm.w;
    }
  }
  __syncthreads();
  // PV
  float acc[16];
  #pragma unroll
  for (int r = 0; r < 16; ++r) acc[r] = 0.f;
  {
    int d = t & 63, cch = t >> 6;
    const float* vp = qkv + 1792 + h * HD + d;
    for (int j = cch * 256; j < cch * 256 + 256; ++j) {
      float vv = vp[(size_t)j * QKVN];
      #pragma unroll
      for (int q = 0; q < 4; ++q) {
        float4 pv = *reinterpret_cast<const float4*>(&p[j][q * 4]);
        acc[q * 4 + 0] += pv.x * vv; acc[q * 4 + 1] += pv.y * vv;
        acc[q * 4 + 2] += pv.z * vv; acc[q * 4 + 3] += pv.w * vv;
      }
    }
  }
  __syncthreads();                 // all p reads done; reuse p as partial buffer
  float* part = &p[0][0];          // [4][16][64]
  {
    int d = t & 63, cch = t >> 6;
    #pragma unroll
    for (int r = 0; r < 16; ++r) part[(cch * 16 + r) * 64 + d] = acc[r];
  }
  __syncthreads();
  for (int k = t; k < 16 * 64; k += 256) {
    int r = k >> 6, dd = k & 63;
    float o = (part[(0 * 16 + r) * 64 + dd] + part[(1 * 16 + r) * 64 + dd] +
               part[(2 * 16 + r) * 64 + dd] + part[(3 * 16 + r) * 64 + dd]) * rsum[r];
    concat[(i0 + r) * DIMX + 128 + h * HD + dd] = f2b_rne(o);
  }
}

// ---------------- bf16 MFMA GEMM: C = A * B^T (+bias), A:MxK, B:NxK ----------------
template <int HAS_BIAS>
__global__ __launch_bounds__(256) void k_gemm(
    const unsigned short* __restrict__ A, const unsigned short* __restrict__ B,
    float* __restrict__ C, const float* __restrict__ bias, int M, int N, int K) {
  const int LDT = 72;  // padded LDS row stride (shorts): kills 32-bank row aliasing
  __shared__ unsigned short As[64 * LDT];
  __shared__ unsigned short Bs[64 * LDT];
  int t = threadIdx.x;
  int lane = t & 63, w = t >> 6;
  int wr = w >> 1, wc = w & 1;
  int mb = blockIdx.y * 64, nb = blockIdx.x * 64;
  f32x4 acc[2][2] = {};
  int r0 = t >> 3;         // 0..31
  int c0 = (t & 7) * 8;    // element offset
  for (int kb = 0; kb < K; kb += 64) {
    bf16x8 av0 = *reinterpret_cast<const bf16x8*>(A + (size_t)(mb + r0) * K + kb + c0);
    bf16x8 av1 = *reinterpret_cast<const bf16x8*>(A + (size_t)(mb + r0 + 32) * K + kb + c0);
    bf16x8 bv0 = *reinterpret_cast<const bf16x8*>(B + (size_t)(nb + r0) * K + kb + c0);
    bf16x8 bv1 = *reinterpret_cast<const bf16x8*>(B + (size_t)(nb + r0 + 32) * K + kb + c0);
    __syncthreads();
    *reinterpret_cast<bf16x8*>(&As[r0 * LDT + c0]) = av0;
    *reinterpret_cast<bf16x8*>(&As[(r0 + 32) * LDT + c0]) = av1;
    *reinterpret_cast<bf16x8*>(&Bs[r0 * LDT + c0]) = bv0;
    *reinterpret_cast<bf16x8*>(&Bs[(r0 + 32) * LDT + c0]) = bv1;
    __syncthreads();
    #pragma unroll
    for (int kk = 0; kk < 2; ++kk) {
      bf16x8 af[2], bfr[2];
      #pragma unroll
      for (int m = 0; m < 2; ++m)
        af[m] = *reinterpret_cast<const bf16x8*>(
            &As[(wr * 32 + m * 16 + (lane & 15)) * LDT + kk * 32 + (lane >> 4) * 8]);
      #pragma unroll
      for (int n = 0; n < 2; ++n)
        bfr[n] = *reinterpret_cast<const bf16x8*>(
            &Bs[(wc * 32 + n * 16 + (lane & 15)) * LDT + kk * 32 + (lane >> 4) * 8]);
      #pragma unroll
      for (int m = 0; m < 2; ++m)
        #pragma unroll
        for (int n = 0; n < 2; ++n)
          acc[m][n] = __builtin_amdgcn_mfma_f32_16x16x32_bf16(af[m], bfr[n], acc[m][n], 0, 0, 0);
    }
  }
  #pragma unroll
  for (int m = 0; m < 2; ++m) {
    int row0 = mb + wr * 32 + m * 16 + (lane >> 4) * 4;
    #pragma unroll
    for (int n = 0; n < 2; ++n) {
      int col = nb + wc * 32 + n * 16 + (lane & 15);
      float bval = HAS_BIAS ? bias[col] : 0.0f;
      #pragma unroll
      for (int r = 0; r < 4; ++r)
        C[(size_t)(row0 + r) * N + col] = acc[m][n][r] + bval;
    }
  }
}

extern "C" void kernel_launch(void* const* d_in, const int* in_sizes, int n_in,
                              void* d_out, int out_size, void* d_ws, size_t ws_size,
                              hipStream_t stream) {
  const float* x      = (const float*)d_in[0];
  const float* qsW    = (const float*)d_in[1];
  const float* qsb    = (const float*)d_in[2];
  const float* lng    = (const float*)d_in[3];
  const float* lnb    = (const float*)d_in[4];
  const float* qfreq  = (const float*)d_in[5];
  const float* qshift = (const float*)d_in[6];
  const float* Wq     = (const float*)d_in[7];
  const float* Wk     = (const float*)d_in[8];
  const float* Wv     = (const float*)d_in[9];
  const float* Wo     = (const float*)d_in[10];
  const float* bo     = (const float*)d_in[11];
  float* out = (float*)d_out;

  char* ws = (char*)d_ws;
  size_t off = 0;
  auto alloc = [&](size_t bytes) { char* p = ws + off; off += (bytes + 255) & ~(size_t)255; return p; };
  float*          tbl       = (float*)alloc(STEPS * 4);
  unsigned short* x_bf      = (unsigned short*)alloc((size_t)SEQ * DIMX * 2);
  unsigned short* wqkv_bf   = (unsigned short*)alloc((size_t)QKVN * DIMX * 2);
  unsigned short* wo_bf     = (unsigned short*)alloc((size_t)DIMX * DIMX * 2);
  unsigned short* concat_bf = (unsigned short*)alloc((size_t)SEQ * DIMX * 2);
  float*          qkv       = (float*)alloc((size_t)SEQ * QKVN * 4);
  float*          amp       = (float*)alloc((size_t)QH * SEQ * HD * 4);
  float*          uu        = (float*)alloc((size_t)QH * SEQ * HD * 4);

  k_table<<<8, 256, 0, stream>>>(tbl);
  k_f2b<<<1024, 256, 0, stream>>>(x, x_bf, SEQ * DIMX);
  k_f2b<<<896, 256, 0, stream>>>(Wq, wqkv_bf, 896 * DIMX);
  k_f2b<<<896, 256, 0, stream>>>(Wk, wqkv_bf + 896 * DIMX, 896 * DIMX);
  k_f2b<<<896, 256, 0, stream>>>(Wv, wqkv_bf + 2 * 896 * DIMX, 896 * DIMX);
  k_f2b<<<1024, 256, 0, stream>>>(Wo, wo_bf, DIMX * DIMX);
  k_qprep<<<QH * SEQ, 128, 0, stream>>>(x, qsW, qsb, lng, lnb, qfreq, amp, uu);
  k_gemm<0><<<dim3(QKVN / 64, SEQ / 64), 256, 0, stream>>>(x_bf, wqkv_bf, qkv, nullptr, SEQ, QKVN, DIMX);
  k_qattn<<<QH * 256, 256, 0, stream>>>(x, tbl, amp, uu, qshift, concat_bf);
  k_tattn<<<dim3(64, TH), 256, 0, stream>>>(qkv, concat_bf);
  k_gemm<1><<<dim3(DIMX / 64, SEQ / 64), 256, 0, stream>>>(concat_bf, wo_bf, out, bo, SEQ, DIMX, DIMX);
}

// Round 2
// 193.536 us; speedup vs baseline: 3.2694x; 3.2694x over previous
//
#include <hip/hip_runtime.h>
#include <hip/hip_bf16.h>
#include <math.h>

#define DIMX 1024
#define SEQ  1024
#define HD   64
#define QH   2
#define TH   14
#define STEPS 2048
#define QKVN 2688   // 3*896
#define LN_EPS 1e-5f

typedef __bf16 bf16x8 __attribute__((ext_vector_type(8)));
typedef float  f32x4  __attribute__((ext_vector_type(4)));
typedef unsigned short u16x8 __attribute__((ext_vector_type(8)));

__device__ inline unsigned short f2b_rne(float f) {
  unsigned int u = __float_as_uint(f);
  unsigned int r = (u + 0x7FFF + ((u >> 16) & 1)) >> 16;
  return (unsigned short)r;
}

__device__ inline float waveRedSum(float v) {
  #pragma unroll
  for (int off = 32; off; off >>= 1) v += __shfl_xor(v, off, 64);
  return v;
}
__device__ inline float waveRedMax(float v) {
  #pragma unroll
  for (int off = 32; off; off >>= 1) v = fmaxf(v, __shfl_xor(v, off, 64));
  return v;
}

// ---------------- cos table ----------------
__global__ void k_table(float* __restrict__ tbl) {
  int t = blockIdx.x * blockDim.x + threadIdx.x;
  if (t < STEPS) tbl[t] = cosf((float)t * (float)(2.0 * M_PI / (STEPS - 1)));
}

// ---------------- f32 -> bf16 convert ----------------
__global__ void k_f2b(const float* __restrict__ src, unsigned short* __restrict__ dst, int n) {
  int i = (blockIdx.x * blockDim.x + threadIdx.x) * 4;
  if (i >= n) return;
  float4 v = *reinterpret_cast<const float4*>(src + i);
  ushort4 o;
  o.x = f2b_rne(v.x); o.y = f2b_rne(v.y); o.z = f2b_rne(v.z); o.w = f2b_rne(v.w);
  *reinterpret_cast<ushort4*>(dst + i) = o;
}

// ---------------- quantum prep: qs = tanh(LN(xh@qsW^T+b)); amp, u=phase*freq*c ----------------
__global__ __launch_bounds__(128) void k_qprep(
    const float* __restrict__ x, const float* __restrict__ qsW,
    const float* __restrict__ qsb, const float* __restrict__ lng,
    const float* __restrict__ lnb, const float* __restrict__ qfreq,
    float* __restrict__ amp, float* __restrict__ u) {
  int b = blockIdx.x; int h = b >> 10; int i = b & 1023;
  int o = threadIdx.x;  // 0..127
  __shared__ float xrow[HD];
  __shared__ float red[4];
  if (o < HD) xrow[o] = x[i * DIMX + h * HD + o];
  __syncthreads();
  float s = qsb[o];
  #pragma unroll
  for (int d = 0; d < HD; d += 4) {
    float4 w = *reinterpret_cast<const float4*>(qsW + o * HD + d);
    float4 xv = *reinterpret_cast<const float4*>(&xrow[d]);
    s += xv.x * w.x + xv.y * w.y + xv.z * w.z + xv.w * w.w;
  }
  int wid = o >> 6, lane = o & 63;
  float ws = waveRedSum(s);
  if (lane == 0) red[wid] = ws;
  __syncthreads();
  float mu = (red[0] + red[1]) * (1.0f / 128.0f);
  float dv = s - mu;
  float ws2 = waveRedSum(dv * dv);
  if (lane == 0) red[2 + wid] = ws2;
  __syncthreads();
  float var = (red[2] + red[3]) * (1.0f / 128.0f);
  float y = dv * rsqrtf(var + LN_EPS) * lng[o] + lnb[o];
  float q = tanhf(y);
  const float c = 325.9493234522016f;  // 2048/(2*pi)
  if (o < HD) amp[(h * 1024 + i) * HD + o] = q;
  else        u[(h * 1024 + i) * HD + (o - HD)] = q * (qfreq[h] * c);
}

// ---------------- quantum attention: 4 rows per block ----------------
__global__ __launch_bounds__(256) void k_qattn(
    const float* __restrict__ x, const float* __restrict__ tbl,
    const float* __restrict__ amp, const float* __restrict__ u,
    const float* __restrict__ qshift, unsigned short* __restrict__ concat) {
  int blk = blockIdx.x; int h = blk >> 8; int ib = blk & 255;
  int i0 = ib * 4;
  int t = threadIdx.x;
  __shared__ float  stbl[STEPS];      // 8KB
  __shared__ float2 uamp[4][HD];      // 2KB (u'+s0, amp)
  __shared__ float  p[4][SEQ];        // 16KB
  __shared__ float  rowsum[4];
  __shared__ float  part[4][4][HD];   // 4KB
  for (int k = t; k < STEPS; k += 256) stbl[k] = tbl[k];
  float s0 = qshift[h] * 325.9493234522016f;
  for (int k = t; k < 4 * HD; k += 256) {
    int ii = k >> 6, d = k & 63;
    uamp[ii][d] = make_float2(u[(h * 1024 + i0 + ii) * HD + d] + s0,
                              amp[(h * 1024 + i0 + ii) * HD + d]);
  }
  __syncthreads();
  const float inv2048 = 1.0f / 2048.0f;
  for (int jt = 0; jt < 4; ++jt) {
    int j = jt * 256 + t;
    const float* uj = &u[(h * 1024 + j) * HD];
    const float* aj = &amp[(h * 1024 + j) * HD];
    float acc[4] = {0.f, 0.f, 0.f, 0.f};
    for (int d0 = 0; d0 < HD; d0 += 4) {
      float4 u4 = *reinterpret_cast<const float4*>(uj + d0);
      float4 a4 = *reinterpret_cast<const float4*>(aj + d0);
      #pragma unroll
      for (int e = 0; e < 4; ++e) {
        float uje = (e == 0) ? u4.x : (e == 1) ? u4.y : (e == 2) ? u4.z : u4.w;
        float aje = (e == 0) ? a4.x : (e == 1) ? a4.y : (e == 2) ? a4.z : a4.w;
        int d = d0 + e;
        #pragma unroll
        for (int ii = 0; ii < 4; ++ii) {
          float2 ua = uamp[ii][d];
          float val = ua.x - uje;
          float q = floorf(val * inv2048);
          float m = fmaf(-2048.0f, q, val);
          int idx = ((int)m) & 2047;
          acc[ii] += ua.y * aje * stbl[idx];
        }
      }
    }
    p[0][j] = acc[0]; p[1][j] = acc[1]; p[2][j] = acc[2]; p[3][j] = acc[3];
  }
  __syncthreads();
  {
    int wid = t >> 6, lane = t & 63;
    float mx = -1e30f;
    for (int jj = 0; jj < 16; ++jj) mx = fmaxf(mx, p[wid][jj * 64 + lane]);
    mx = waveRedMax(mx);
    float sum = 0.f;
    for (int jj = 0; jj < 16; ++jj) {
      int j = jj * 64 + lane;
      float e = __expf((p[wid][j] - mx) * 0.125f);
      p[wid][j] = e;
      sum += e;
    }
    sum = waveRedSum(sum);
    if (lane == 0) rowsum[wid] = 1.0f / sum;
  }
  __syncthreads();
  {
    int d = t & 63, cch = t >> 6;
    float acc[4] = {0.f, 0.f, 0.f, 0.f};
    const float* xp = x + h * HD + d;
    for (int j = cch * 256; j < cch * 256 + 256; ++j) {
      float xv = xp[j * DIMX];
      #pragma unroll
      for (int ii = 0; ii < 4; ++ii) acc[ii] += p[ii][j] * xv;
    }
    #pragma unroll
    for (int ii = 0; ii < 4; ++ii) part[cch][ii][d] = acc[ii];
  }
  __syncthreads();
  {
    int ii = t >> 6, dd = t & 63;
    float o = (part[0][ii][dd] + part[1][ii][dd] + part[2][ii][dd] + part[3][ii][dd]) * rowsum[ii];
    concat[(i0 + ii) * DIMX + h * HD + dd] = f2b_rne(o);
  }
}

// ---------------- V transpose: qkv[kv][1792+h*64+d] -> vt[h][d][kv] (bf16) ----------------
__global__ __launch_bounds__(256) void k_vt(const unsigned short* __restrict__ qkv,
                                            unsigned short* __restrict__ vt) {
  int h = blockIdx.y, kv0 = blockIdx.x * 64;
  int t = threadIdx.x;
  __shared__ unsigned short tile[64][72];
  #pragma unroll
  for (int pass = 0; pass < 2; ++pass) {
    int s = pass * 256 + t;
    int r = s >> 3, c8 = (s & 7) * 8;
    u16x8 v = *reinterpret_cast<const u16x8*>(qkv + (size_t)(kv0 + r) * QKVN + 1792 + h * 64 + c8);
    *reinterpret_cast<u16x8*>(&tile[r][c8]) = v;
  }
  __syncthreads();
  #pragma unroll
  for (int pass = 0; pass < 2; ++pass) {
    int s = pass * 256 + t;
    int d = s >> 3, k8 = (s & 7) * 8;
    u16x8 o;
    #pragma unroll
    for (int j = 0; j < 8; ++j) o[j] = tile[k8 + j][d];
    *reinterpret_cast<u16x8*>(vt + (size_t)h * 65536 + (size_t)d * 1024 + kv0 + k8) = o;
  }
}

// ---------------- softmax: f32 scores row -> normalized bf16 P row (scale 1/8 folded) ----
__global__ __launch_bounds__(256) void k_softmax(const float* __restrict__ s,
                                                 unsigned short* __restrict__ p) {
  int row = blockIdx.x * 4 + (threadIdx.x >> 6);
  int lane = threadIdx.x & 63;
  const float* sr = s + (size_t)row * 1024;
  float4 v[4];
  float mx = -1e30f;
  #pragma unroll
  for (int q = 0; q < 4; ++q) {
    v[q] = *reinterpret_cast<const float4*>(sr + q * 256 + lane * 4);
    mx = fmaxf(mx, fmaxf(fmaxf(v[q].x, v[q].y), fmaxf(v[q].z, v[q].w)));
  }
  mx = waveRedMax(mx);
  float sum = 0.f;
  #pragma unroll
  for (int q = 0; q < 4; ++q) {
    v[q].x = __expf((v[q].x - mx) * 0.125f); sum += v[q].x;
    v[q].y = __expf((v[q].y - mx) * 0.125f); sum += v[q].y;
    v[q].z = __expf((v[q].z - mx) * 0.125f); sum += v[q].z;
    v[q].w = __expf((v[q].w - mx) * 0.125f); sum += v[q].w;
  }
  sum = waveRedSum(sum);
  float inv = 1.0f / sum;
  unsigned short* pr = p + (size_t)row * 1024;
  #pragma unroll
  for (int q = 0; q < 4; ++q) {
    ushort4 o;
    o.x = f2b_rne(v[q].x * inv); o.y = f2b_rne(v[q].y * inv);
    o.z = f2b_rne(v[q].z * inv); o.w = f2b_rne(v[q].w * inv);
    *reinterpret_cast<ushort4*>(pr + q * 256 + lane * 4) = o;
  }
}

// ---------------- batched bf16 MFMA GEMM: C = A * B^T (+bias), strided ----------------
// A: rows use lda, B: rows use ldb; batch z adds a_batch/b_batch/c_batch (elements).
template <int HAS_BIAS, int BF16_OUT>
__global__ __launch_bounds__(256) void k_bgemm(
    const unsigned short* __restrict__ A, const unsigned short* __restrict__ B,
    void* __restrict__ Cv, const float* __restrict__ bias,
    int K, int lda, int ldb, int ldc,
    long a_batch, long b_batch, long c_batch) {
  const int LDT = 72;  // padded LDS row stride (shorts)
  __shared__ unsigned short As[64 * LDT];
  __shared__ unsigned short Bs[64 * LDT];
  int t = threadIdx.x;
  int lane = t & 63, w = t >> 6;
  int wr = w >> 1, wc = w & 1;
  int mb = blockIdx.y * 64, nb = blockIdx.x * 64;
  const unsigned short* Ab = A + (size_t)blockIdx.z * a_batch;
  const unsigned short* Bb = B + (size_t)blockIdx.z * b_batch;
  f32x4 acc[2][2] = {};
  int r0 = t >> 3;         // 0..31
  int c0 = (t & 7) * 8;    // element offset
  for (int kb = 0; kb < K; kb += 64) {
    bf16x8 av0 = *reinterpret_cast<const bf16x8*>(Ab + (size_t)(mb + r0) * lda + kb + c0);
    bf16x8 av1 = *reinterpret_cast<const bf16x8*>(Ab + (size_t)(mb + r0 + 32) * lda + kb + c0);
    bf16x8 bv0 = *reinterpret_cast<const bf16x8*>(Bb + (size_t)(nb + r0) * ldb + kb + c0);
    bf16x8 bv1 = *reinterpret_cast<const bf16x8*>(Bb + (size_t)(nb + r0 + 32) * ldb + kb + c0);
    __syncthreads();
    *reinterpret_cast<bf16x8*>(&As[r0 * LDT + c0]) = av0;
    *reinterpret_cast<bf16x8*>(&As[(r0 + 32) * LDT + c0]) = av1;
    *reinterpret_cast<bf16x8*>(&Bs[r0 * LDT + c0]) = bv0;
    *reinterpret_cast<bf16x8*>(&Bs[(r0 + 32) * LDT + c0]) = bv1;
    __syncthreads();
    #pragma unroll
    for (int kk = 0; kk < 2; ++kk) {
      bf16x8 af[2], bfr[2];
      #pragma unroll
      for (int m = 0; m < 2; ++m)
        af[m] = *reinterpret_cast<const bf16x8*>(
            &As[(wr * 32 + m * 16 + (lane & 15)) * LDT + kk * 32 + (lane >> 4) * 8]);
      #pragma unroll
      for (int n = 0; n < 2; ++n)
        bfr[n] = *reinterpret_cast<const bf16x8*>(
            &Bs[(wc * 32 + n * 16 + (lane & 15)) * LDT + kk * 32 + (lane >> 4) * 8]);
      #pragma unroll
      for (int m = 0; m < 2; ++m)
        #pragma unroll
        for (int n = 0; n < 2; ++n)
          acc[m][n] = __builtin_amdgcn_mfma_f32_16x16x32_bf16(af[m], bfr[n], acc[m][n], 0, 0, 0);
    }
  }
  #pragma unroll
  for (int m = 0; m < 2; ++m) {
    int row0 = mb + wr * 32 + m * 16 + (lane >> 4) * 4;
    #pragma unroll
    for (int n = 0; n < 2; ++n) {
      int col = nb + wc * 32 + n * 16 + (lane & 15);
      float bval = HAS_BIAS ? bias[col] : 0.0f;
      #pragma unroll
      for (int r = 0; r < 4; ++r) {
        size_t idx = (size_t)blockIdx.z * c_batch + (size_t)(row0 + r) * ldc + col;
        if (BF16_OUT) ((unsigned short*)Cv)[idx] = f2b_rne(acc[m][n][r] + bval);
        else          ((float*)Cv)[idx] = acc[m][n][r] + bval;
      }
    }
  }
}

extern "C" void kernel_launch(void* const* d_in, const int* in_sizes, int n_in,
                              void* d_out, int out_size, void* d_ws, size_t ws_size,
                              hipStream_t stream) {
  const float* x      = (const float*)d_in[0];
  const float* qsW    = (const float*)d_in[1];
  const float* qsb    = (const float*)d_in[2];
  const float* lng    = (const float*)d_in[3];
  const float* lnb    = (const float*)d_in[4];
  const float* qfreq  = (const float*)d_in[5];
  const float* qshift = (const float*)d_in[6];
  const float* Wq     = (const float*)d_in[7];
  const float* Wk     = (const float*)d_in[8];
  const float* Wv     = (const float*)d_in[9];
  const float* Wo     = (const float*)d_in[10];
  const float* bo     = (const float*)d_in[11];
  float* out = (float*)d_out;

  char* ws = (char*)d_ws;
  size_t off = 0;
  auto alloc = [&](size_t bytes) { char* p = ws + off; off += (bytes + 255) & ~(size_t)255; return p; };
  float*          tbl       = (float*)alloc(STEPS * 4);
  unsigned short* x_bf      = (unsigned short*)alloc((size_t)SEQ * DIMX * 2);
  unsigned short* wqkv_bf   = (unsigned short*)alloc((size_t)QKVN * DIMX * 2);
  unsigned short* wo_bf     = (unsigned short*)alloc((size_t)DIMX * DIMX * 2);
  unsigned short* concat_bf = (unsigned short*)alloc((size_t)SEQ * DIMX * 2);
  unsigned short* qkv_bf    = (unsigned short*)alloc((size_t)SEQ * QKVN * 2);
  float*          amp       = (float*)alloc((size_t)QH * SEQ * HD * 4);
  float*          uu        = (float*)alloc((size_t)QH * SEQ * HD * 4);
  unsigned short* vt        = (unsigned short*)alloc((size_t)TH * HD * SEQ * 2);
  float*          scores    = (float*)alloc((size_t)7 * SEQ * SEQ * 4);     // chunk of 7 heads
  unsigned short* p_bf      = (unsigned short*)alloc((size_t)7 * SEQ * SEQ * 2);

  k_table<<<8, 256, 0, stream>>>(tbl);
  k_f2b<<<1024, 256, 0, stream>>>(x, x_bf, SEQ * DIMX);
  k_f2b<<<896, 256, 0, stream>>>(Wq, wqkv_bf, 896 * DIMX);
  k_f2b<<<896, 256, 0, stream>>>(Wk, wqkv_bf + 896 * DIMX, 896 * DIMX);
  k_f2b<<<896, 256, 0, stream>>>(Wv, wqkv_bf + 2 * 896 * DIMX, 896 * DIMX);
  k_f2b<<<1024, 256, 0, stream>>>(Wo, wo_bf, DIMX * DIMX);
  k_qprep<<<QH * SEQ, 128, 0, stream>>>(x, qsW, qsb, lng, lnb, qfreq, amp, uu);

  // QKV projection -> bf16 qkv
  k_bgemm<0, 1><<<dim3(QKVN / 64, SEQ / 64, 1), 256, 0, stream>>>(
      x_bf, wqkv_bf, qkv_bf, nullptr, DIMX, DIMX, DIMX, QKVN, 0, 0, 0);

  k_qattn<<<QH * 256, 256, 0, stream>>>(x, tbl, amp, uu, qshift, concat_bf);
  k_vt<<<dim3(16, TH), 256, 0, stream>>>(qkv_bf, vt);

  // trad attention in two 7-head chunks
  for (int c = 0; c < 2; ++c) {
    int h0 = c * 7;
    // scores: S[z][q][kv] = Q_z . K_z^T  (f32)
    k_bgemm<0, 0><<<dim3(16, 16, 7), 256, 0, stream>>>(
        qkv_bf + h0 * 64, qkv_bf + 896 + h0 * 64, scores, nullptr,
        HD, QKVN, QKVN, SEQ, 64, 64, (long)SEQ * SEQ);
    k_softmax<<<7 * SEQ / 4, 256, 0, stream>>>(scores, p_bf);
    // PV: out[z][q][d] = P . Vt^T -> concat cols 128 + (h0+z)*64
    k_bgemm<0, 1><<<dim3(1, 16, 7), 256, 0, stream>>>(
        p_bf, vt + (size_t)h0 * HD * SEQ, concat_bf + 128 + h0 * 64, nullptr,
        SEQ, SEQ, SEQ, DIMX, (long)SEQ * SEQ, (long)HD * SEQ, 64);
  }

  // output projection
  k_bgemm<1, 0><<<dim3(DIMX / 64, SEQ / 64, 1), 256, 0, stream>>>(
      concat_bf, wo_bf, out, bo, DIMX, DIMX, DIMX, DIMX, 0, 0, 0);
}

// Round 4
// 137.600 us; speedup vs baseline: 4.5984x; 1.4065x over previous
//
#include <hip/hip_runtime.h>
#include <hip/hip_bf16.h>
#include <math.h>

#define DIMX 1024
#define SEQ  1024
#define HD   64
#define QH   2
#define TH   14
#define QKVN 2688   // 3*896
#define LN_EPS 1e-5f

typedef __bf16 bf16x8 __attribute__((ext_vector_type(8)));
typedef float  f32x4  __attribute__((ext_vector_type(4)));
typedef unsigned short u16x8 __attribute__((ext_vector_type(8)));

__device__ inline unsigned short f2b_rne(float f) {
  unsigned int u = __float_as_uint(f);
  unsigned int r = (u + 0x7FFF + ((u >> 16) & 1)) >> 16;
  return (unsigned short)r;
}

__device__ inline float waveRedSum(float v) {
  #pragma unroll
  for (int off = 32; off; off >>= 1) v += __shfl_xor(v, off, 64);
  return v;
}
__device__ inline float waveRedMax(float v) {
  #pragma unroll
  for (int off = 32; off; off >>= 1) v = fmaxf(v, __shfl_xor(v, off, 64));
  return v;
}

// ---------------- f32 -> bf16 convert ----------------
__global__ void k_f2b(const float* __restrict__ src, unsigned short* __restrict__ dst, int n) {
  int i = (blockIdx.x * blockDim.x + threadIdx.x) * 4;
  if (i >= n) return;
  float4 v = *reinterpret_cast<const float4*>(src + i);
  ushort4 o;
  o.x = f2b_rne(v.x); o.y = f2b_rne(v.y); o.z = f2b_rne(v.z); o.w = f2b_rne(v.w);
  *reinterpret_cast<ushort4*>(dst + i) = o;
}

// ---------------- quantum prep ----------------
// qs = tanh(LN(xh@qsW^T+b)); amp=qs[:64], phase=qs[64:]
// qcs[h][i][0:64] = amp*cos(phase*f+s), [64:128] = amp*sin(phase*f+s)   (query side)
// kcs[h][j][0:64] = amp*cos(phase*f),   [64:128] = amp*sin(phase*f)     (key side)
__global__ __launch_bounds__(128) void k_qprep(
    const float* __restrict__ x, const float* __restrict__ qsW,
    const float* __restrict__ qsb, const float* __restrict__ lng,
    const float* __restrict__ lnb, const float* __restrict__ qfreq,
    const float* __restrict__ qshift,
    unsigned short* __restrict__ qcs, unsigned short* __restrict__ kcs) {
  int b = blockIdx.x; int h = b >> 10; int i = b & 1023;
  int o = threadIdx.x;  // 0..127
  __shared__ float xrow[HD];
  __shared__ float red[4];
  __shared__ float qsv[128];
  if (o < HD) xrow[o] = x[i * DIMX + h * HD + o];
  __syncthreads();
  float s = qsb[o];
  #pragma unroll
  for (int d = 0; d < HD; d += 4) {
    float4 w = *reinterpret_cast<const float4*>(qsW + o * HD + d);
    float4 xv = *reinterpret_cast<const float4*>(&xrow[d]);
    s += xv.x * w.x + xv.y * w.y + xv.z * w.z + xv.w * w.w;
  }
  int wid = o >> 6, lane = o & 63;
  float ws = waveRedSum(s);
  if (lane == 0) red[wid] = ws;
  __syncthreads();
  float mu = (red[0] + red[1]) * (1.0f / 128.0f);
  float dv = s - mu;
  float ws2 = waveRedSum(dv * dv);
  if (lane == 0) red[2 + wid] = ws2;
  __syncthreads();
  float var = (red[2] + red[3]) * (1.0f / 128.0f);
  float y = dv * rsqrtf(var + LN_EPS) * lng[o] + lnb[o];
  qsv[o] = tanhf(y);
  __syncthreads();
  float freq = qfreq[h], shift = qshift[h];
  size_t base = ((size_t)h * 1024 + i) * 128;
  if (o < HD) {
    float amp = qsv[o];
    float a = qsv[64 + o] * freq + shift;
    float sn, cs;
    __sincosf(a, &sn, &cs);
    qcs[base + o]      = f2b_rne(amp * cs);
    qcs[base + 64 + o] = f2b_rne(amp * sn);
  } else {
    int d = o - 64;
    float amp = qsv[d];
    float bAng = qsv[64 + d] * freq;
    float sn, cs;
    __sincosf(bAng, &sn, &cs);
    kcs[base + d]      = f2b_rne(amp * cs);
    kcs[base + 64 + d] = f2b_rne(amp * sn);
  }
}

// ---------------- 64-col block transpose: src[kv][col0+h*64+d] -> dst[h][d][kv] ----------------
__global__ __launch_bounds__(256) void k_tr64(const unsigned short* __restrict__ src, int ld,
                                              int col0, unsigned short* __restrict__ dst) {
  int h = blockIdx.y, kv0 = blockIdx.x * 64;
  int t = threadIdx.x;
  __shared__ unsigned short tile[64][72];
  #pragma unroll
  for (int pass = 0; pass < 2; ++pass) {
    int s = pass * 256 + t;
    int r = s >> 3, c8 = (s & 7) * 8;
    u16x8 v = *reinterpret_cast<const u16x8*>(src + (size_t)(kv0 + r) * ld + col0 + h * 64 + c8);
    *reinterpret_cast<u16x8*>(&tile[r][c8]) = v;
  }
  __syncthreads();
  #pragma unroll
  for (int pass = 0; pass < 2; ++pass) {
    int s = pass * 256 + t;
    int d = s >> 3, k8 = (s & 7) * 8;
    u16x8 o;
    #pragma unroll
    for (int j = 0; j < 8; ++j) o[j] = tile[k8 + j][d];
    *reinterpret_cast<u16x8*>(dst + (size_t)h * 65536 + (size_t)d * 1024 + kv0 + k8) = o;
  }
}

// ---------------- softmax: f32 scores row -> normalized bf16 P row (scale 1/8 folded) ----
__global__ __launch_bounds__(256) void k_softmax(const float* __restrict__ s,
                                                 unsigned short* __restrict__ p) {
  int row = blockIdx.x * 4 + (threadIdx.x >> 6);
  int lane = threadIdx.x & 63;
  const float* sr = s + (size_t)row * 1024;
  float4 v[4];
  float mx = -1e30f;
  #pragma unroll
  for (int q = 0; q < 4; ++q) {
    v[q] = *reinterpret_cast<const float4*>(sr + q * 256 + lane * 4);
    mx = fmaxf(mx, fmaxf(fmaxf(v[q].x, v[q].y), fmaxf(v[q].z, v[q].w)));
  }
  mx = waveRedMax(mx);
  float sum = 0.f;
  #pragma unroll
  for (int q = 0; q < 4; ++q) {
    v[q].x = __expf((v[q].x - mx) * 0.125f); sum += v[q].x;
    v[q].y = __expf((v[q].y - mx) * 0.125f); sum += v[q].y;
    v[q].z = __expf((v[q].z - mx) * 0.125f); sum += v[q].z;
    v[q].w = __expf((v[q].w - mx) * 0.125f); sum += v[q].w;
  }
  sum = waveRedSum(sum);
  float inv = 1.0f / sum;
  unsigned short* pr = p + (size_t)row * 1024;
  #pragma unroll
  for (int q = 0; q < 4; ++q) {
    ushort4 o;
    o.x = f2b_rne(v[q].x * inv); o.y = f2b_rne(v[q].y * inv);
    o.z = f2b_rne(v[q].z * inv); o.w = f2b_rne(v[q].w * inv);
    *reinterpret_cast<ushort4*>(pr + q * 256 + lane * 4) = o;
  }
}

// ---------------- batched bf16 MFMA GEMM: C = A * B^T (+bias), strided ----------------
template <int HAS_BIAS, int BF16_OUT>
__global__ __launch_bounds__(256) void k_bgemm(
    const unsigned short* __restrict__ A, const unsigned short* __restrict__ B,
    void* __restrict__ Cv, const float* __restrict__ bias,
    int K, int lda, int ldb, int ldc,
    long a_batch, long b_batch, long c_batch) {
  const int LDT = 72;  // padded LDS row stride (shorts)
  __shared__ unsigned short As[64 * LDT];
  __shared__ unsigned short Bs[64 * LDT];
  int t = threadIdx.x;
  int lane = t & 63, w = t >> 6;
  int wr = w >> 1, wc = w & 1;
  int mb = blockIdx.y * 64, nb = blockIdx.x * 64;
  const unsigned short* Ab = A + (size_t)blockIdx.z * a_batch;
  const unsigned short* Bb = B + (size_t)blockIdx.z * b_batch;
  f32x4 acc[2][2] = {};
  int r0 = t >> 3;         // 0..31
  int c0 = (t & 7) * 8;    // element offset
  for (int kb = 0; kb < K; kb += 64) {
    bf16x8 av0 = *reinterpret_cast<const bf16x8*>(Ab + (size_t)(mb + r0) * lda + kb + c0);
    bf16x8 av1 = *reinterpret_cast<const bf16x8*>(Ab + (size_t)(mb + r0 + 32) * lda + kb + c0);
    bf16x8 bv0 = *reinterpret_cast<const bf16x8*>(Bb + (size_t)(nb + r0) * ldb + kb + c0);
    bf16x8 bv1 = *reinterpret_cast<const bf16x8*>(Bb + (size_t)(nb + r0 + 32) * ldb + kb + c0);
    __syncthreads();
    *reinterpret_cast<bf16x8*>(&As[r0 * LDT + c0]) = av0;
    *reinterpret_cast<bf16x8*>(&As[(r0 + 32) * LDT + c0]) = av1;
    *reinterpret_cast<bf16x8*>(&Bs[r0 * LDT + c0]) = bv0;
    *reinterpret_cast<bf16x8*>(&Bs[(r0 + 32) * LDT + c0]) = bv1;
    __syncthreads();
    #pragma unroll
    for (int kk = 0; kk < 2; ++kk) {
      bf16x8 af[2], bfr[2];
      #pragma unroll
      for (int m = 0; m < 2; ++m)
        af[m] = *reinterpret_cast<const bf16x8*>(
            &As[(wr * 32 + m * 16 + (lane & 15)) * LDT + kk * 32 + (lane >> 4) * 8]);
      #pragma unroll
      for (int n = 0; n < 2; ++n)
        bfr[n] = *reinterpret_cast<const bf16x8*>(
            &Bs[(wc * 32 + n * 16 + (lane & 15)) * LDT + kk * 32 + (lane >> 4) * 8]);
      #pragma unroll
      for (int m = 0; m < 2; ++m)
        #pragma unroll
        for (int n = 0; n < 2; ++n)
          acc[m][n] = __builtin_amdgcn_mfma_f32_16x16x32_bf16(af[m], bfr[n], acc[m][n], 0, 0, 0);
    }
  }
  #pragma unroll
  for (int m = 0; m < 2; ++m) {
    int row0 = mb + wr * 32 + m * 16 + (lane >> 4) * 4;
    #pragma unroll
    for (int n = 0; n < 2; ++n) {
      int col = nb + wc * 32 + n * 16 + (lane & 15);
      float bval = HAS_BIAS ? bias[col] : 0.0f;
      #pragma unroll
      for (int r = 0; r < 4; ++r) {
        size_t idx = (size_t)blockIdx.z * c_batch + (size_t)(row0 + r) * ldc + col;
        if (BF16_OUT) ((unsigned short*)Cv)[idx] = f2b_rne(acc[m][n][r] + bval);
        else          ((float*)Cv)[idx] = acc[m][n][r] + bval;
      }
    }
  }
}

extern "C" void kernel_launch(void* const* d_in, const int* in_sizes, int n_in,
                              void* d_out, int out_size, void* d_ws, size_t ws_size,
                              hipStream_t stream) {
  const float* x      = (const float*)d_in[0];
  const float* qsW    = (const float*)d_in[1];
  const float* qsb    = (const float*)d_in[2];
  const float* lng    = (const float*)d_in[3];
  const float* lnb    = (const float*)d_in[4];
  const float* qfreq  = (const float*)d_in[5];
  const float* qshift = (const float*)d_in[6];
  const float* Wq     = (const float*)d_in[7];
  const float* Wk     = (const float*)d_in[8];
  const float* Wv     = (const float*)d_in[9];
  const float* Wo     = (const float*)d_in[10];
  const float* bo     = (const float*)d_in[11];
  float* out = (float*)d_out;

  char* ws = (char*)d_ws;
  size_t off = 0;
  auto alloc = [&](size_t bytes) { char* p = ws + off; off += (bytes + 255) & ~(size_t)255; return p; };
  unsigned short* x_bf      = (unsigned short*)alloc((size_t)SEQ * DIMX * 2);
  unsigned short* wqkv_bf   = (unsigned short*)alloc((size_t)QKVN * DIMX * 2);
  unsigned short* wo_bf     = (unsigned short*)alloc((size_t)DIMX * DIMX * 2);
  unsigned short* concat_bf = (unsigned short*)alloc((size_t)SEQ * DIMX * 2);
  unsigned short* qkv_bf    = (unsigned short*)alloc((size_t)SEQ * QKVN * 2);
  unsigned short* qcs       = (unsigned short*)alloc((size_t)QH * SEQ * 128 * 2);
  unsigned short* kcs       = (unsigned short*)alloc((size_t)QH * SEQ * 128 * 2);
  unsigned short* vt        = (unsigned short*)alloc((size_t)TH * HD * SEQ * 2);
  unsigned short* xt        = (unsigned short*)alloc((size_t)QH * HD * SEQ * 2);
  float*          scores    = (float*)alloc((size_t)7 * SEQ * SEQ * 4);     // chunk of 7 heads
  unsigned short* p_bf      = (unsigned short*)alloc((size_t)7 * SEQ * SEQ * 2);

  k_f2b<<<1024, 256, 0, stream>>>(x, x_bf, SEQ * DIMX);
  k_f2b<<<896, 256, 0, stream>>>(Wq, wqkv_bf, 896 * DIMX);
  k_f2b<<<896, 256, 0, stream>>>(Wk, wqkv_bf + 896 * DIMX, 896 * DIMX);
  k_f2b<<<896, 256, 0, stream>>>(Wv, wqkv_bf + 2 * 896 * DIMX, 896 * DIMX);
  k_f2b<<<1024, 256, 0, stream>>>(Wo, wo_bf, DIMX * DIMX);
  k_qprep<<<QH * SEQ, 128, 0, stream>>>(x, qsW, qsb, lng, lnb, qfreq, qshift, qcs, kcs);

  // QKV projection -> bf16 qkv
  k_bgemm<0, 1><<<dim3(QKVN / 64, SEQ / 64, 1), 256, 0, stream>>>(
      x_bf, wqkv_bf, qkv_bf, nullptr, DIMX, DIMX, DIMX, QKVN, 0, 0, 0);

  k_tr64<<<dim3(16, TH), 256, 0, stream>>>(qkv_bf, QKVN, 1792, vt);
  k_tr64<<<dim3(16, QH), 256, 0, stream>>>(x_bf, DIMX, 0, xt);

  // quantum heads: scores = qcs @ kcs^T (K=128) -> softmax -> P @ xt^T
  k_bgemm<0, 0><<<dim3(16, 16, QH), 256, 0, stream>>>(
      qcs, kcs, scores, nullptr, 128, 128, 128, SEQ,
      (long)SEQ * 128, (long)SEQ * 128, (long)SEQ * SEQ);
  k_softmax<<<QH * SEQ / 4, 256, 0, stream>>>(scores, p_bf);
  k_bgemm<0, 1><<<dim3(1, 16, QH), 256, 0, stream>>>(
      p_bf, xt, concat_bf, nullptr, SEQ, SEQ, SEQ, DIMX,
      (long)SEQ * SEQ, (long)HD * SEQ, 64);

  // trad attention in two 7-head chunks
  for (int c = 0; c < 2; ++c) {
    int h0 = c * 7;
    k_bgemm<0, 0><<<dim3(16, 16, 7), 256, 0, stream>>>(
        qkv_bf + h0 * 64, qkv_bf + 896 + h0 * 64, scores, nullptr,
        HD, QKVN, QKVN, SEQ, 64, 64, (long)SEQ * SEQ);
    k_softmax<<<7 * SEQ / 4, 256, 0, stream>>>(scores, p_bf);
    k_bgemm<0, 1><<<dim3(1, 16, 7), 256, 0, stream>>>(
        p_bf, vt + (size_t)h0 * HD * SEQ, concat_bf + 128 + h0 * 64, nullptr,
        SEQ, SEQ, SEQ, DIMX, (long)SEQ * SEQ, (long)HD * SEQ, 64);
  }

  // output projection
  k_bgemm<1, 0><<<dim3(DIMX / 64, SEQ / 64, 1), 256, 0, stream>>>(
      concat_bf, wo_bf, out, bo, DIMX, DIMX, DIMX, DIMX, 0, 0, 0);
}